// Round 6
// baseline (31.310 us; speedup 1.0000x reference)
//
#include <hip/hip_runtime.h>
#include <stdint.h>

#define H 512
#define W 512
#define B 8
#define SW 56                      // output columns per wave-strip
#define NSTRIP 10                  // strips cover 512 cols (last is ragged: 8 cols)
#define CH 16                      // output rows per wave
#define NCH (H / CH)               // 32
#define UNITS (NSTRIP * NCH * B)   // 2560 waves
#define WPB 4                      // waves per 256-thread block
#define NBLK (UNITS / WPB)         // 640 blocks

// Wave-autonomous strips: lane l <-> column x0-4+l. One __ballot = one 64-col
// edge-row mask (wave-uniform, SGPR). Rolling 8-row mask window, SALU +/-oy
// folds, per-lane EDT via uniform-mask >> (lane-4), branchless nearest-bit.
// Rolling 4-deep target-class register buffer. No __syncthreads in the hot
// path, no LDS for masks, no atomics.
__global__ __launch_bounds__(256) void seg_main(const float* __restrict__ preds,
                                                const int* __restrict__ tgt,
                                                float* __restrict__ partials) {
    __shared__ float redf[WPB][4];
    __shared__ int redi[WPB][3];

    const int tid = threadIdx.x;
    const int wave = tid >> 6;
    const int lane = tid & 63;

    const int unit = blockIdx.x * WPB + wave;
    const int s = unit % NSTRIP;
    const int t1 = unit / NSTRIP;
    const int ch = t1 % NCH;
    const int b = t1 / NCH;

    const int x0 = s * SW;
    const int y0 = ch * CH;
    const int col = x0 - 4 + lane;
    const bool colok = (col >= 0) & (col < W);
    const bool outl = (lane >= 4) & (lane < 60) & (col < W);
    const int sh = (lane >= 4) ? (lane - 4) : 0;  // mask shift for output lanes

    const int* T = tgt + (size_t)b * H * W;
    const float* Pb = preds + (size_t)b * 3 * H * W;

    // ---- warmup: edge masks for rows y0-4 .. y0+3 -> m[0..7]; stash t of rows y0..y0+3 ----
    unsigned long long m[8];
    int tq[4];
    int tprev = ((y0 - 5 >= 0) & colok) ? T[(size_t)(y0 - 5) * W + col] : 0;
    #pragma unroll
    for (int i = 0; i < 8; ++i) {
        const int r = y0 - 4 + i;
        const bool rok = (r >= 0);  // r < H always in warmup
        int t0 = (rok & colok) ? T[(size_t)r * W + col] : 0;
        int tl = __shfl_up(t0, 1, 64);
        int tl0 = (lane == 0 && x0 > 0 && rok) ? T[(size_t)r * W + x0 - 5] : 0;
        if (lane == 0) tl = (x0 > 0) ? tl0 : t0;
        bool e = rok & colok & (((r > 0) & (t0 != tprev)) | ((col > 0) & (t0 != tl)));
        m[i] = __ballot(e);
        if (i >= 4) tq[i - 4] = t0;
        tprev = t0;
    }

    const unsigned int allowA[5] = {0x1FFu, 0x1FFu, 0x1FFu, 0xFEu, 0x7Cu};

    float s0 = 0.f, s1 = 0.f, s2 = 0.f, s3 = 0.f;  // ce*w, p1*t1, p1, w
    int c_t1 = 0, c_bm = 0, c_ok = 0;              // wave totals via ballot+popc

    #pragma unroll 4
    for (int i = 0; i < CH; ++i) {
        const int y = y0 + i;
        // ---- build mask for row y+4 (r >= 4 so no r>0 guard needed) ----
        const int r = y + 4;
        const bool rok = (r < H);
        int t0 = (rok & colok) ? T[(size_t)r * W + col] : 0;
        int tl = __shfl_up(t0, 1, 64);
        int tl0 = (lane == 0 && x0 > 0 && rok) ? T[(size_t)r * W + x0 - 5] : 0;
        if (lane == 0) tl = (x0 > 0) ? tl0 : t0;
        bool e = rok & colok & ((t0 != tprev) | ((col > 0) & (t0 != tl)));
        unsigned long long mnew = __ballot(e);
        tprev = t0;

        // ---- preds for row y (output lanes only) ----
        const size_t pix = (size_t)y * W + col;
        float p0 = outl ? Pb[pix] : 0.f;
        float p1 = outl ? Pb[pix + (size_t)H * W] : 0.f;
        float p2 = outl ? Pb[pix + 2 * (size_t)H * W] : 0.f;
        const int t = tq[0];

        // ---- folded masks (wave-uniform -> SALU) ----
        unsigned long long f0 = m[4];
        unsigned long long f1 = m[3] | m[5];
        unsigned long long f2 = m[2] | m[6];
        unsigned long long f3 = m[1] | m[7];
        unsigned long long f4 = m[0] | mnew;

        // ---- clipped EDT for (y, col) ----
        int d2min = 25;
        {
            unsigned int bb, u;
            int ax;
            bb = (unsigned int)(f0 >> sh) & allowA[0];
            u = ((bb >> 4) & 31u) | (__brev(bb & 31u) >> 27) | 0x20u;
            ax = __ffs(u) - 1; d2min = min(d2min, ax * ax);
            bb = (unsigned int)(f1 >> sh) & allowA[1];
            u = ((bb >> 4) & 31u) | (__brev(bb & 31u) >> 27) | 0x20u;
            ax = __ffs(u) - 1; d2min = min(d2min, 1 + ax * ax);
            bb = (unsigned int)(f2 >> sh) & allowA[2];
            u = ((bb >> 4) & 31u) | (__brev(bb & 31u) >> 27) | 0x20u;
            ax = __ffs(u) - 1; d2min = min(d2min, 4 + ax * ax);
            bb = (unsigned int)(f3 >> sh) & allowA[3];
            u = ((bb >> 4) & 31u) | (__brev(bb & 31u) >> 27) | 0x20u;
            ax = __ffs(u) - 1; d2min = min(d2min, 9 + ax * ax);
            bb = (unsigned int)(f4 >> sh) & allowA[4];
            u = ((bb >> 4) & 31u) | (__brev(bb & 31u) >> 27) | 0x20u;
            ax = __ffs(u) - 1; d2min = min(d2min, 16 + ax * ax);
        }
        float dist = (d2min >= 25) ? 5.0f : sqrtf((float)d2min);
        float wgt = (d2min >= 25) ? 1.0f : (2.0f - dist * 0.2f);

        // ---- softmax (no max-sub: inputs ~N(0,1)) / CE / dice / argmax ----
        float e0 = __expf(p0), e1 = __expf(p1), e2 = __expf(p2);
        float se = e0 + e1 + e2;
        float lse = __logf(se);
        float pt = (t == 0) ? p0 : ((t == 1) ? p1 : p2);
        float ce = lse - pt;
        float prob1 = e1 * __builtin_amdgcn_rcpf(se);

        int cls = 0;
        float best = p0;
        if (p1 > best) { best = p1; cls = 1; }
        if (p2 > best) { cls = 2; }

        bool bm = wgt > 1.5f;
        c_t1 += __popcll(__ballot(outl & (t == 1)));
        c_bm += __popcll(__ballot(outl & bm));
        c_ok += __popcll(__ballot(outl & bm & (cls == t)));

        s0 += outl ? ce * wgt : 0.f;
        s1 += (outl & (t == 1)) ? prob1 : 0.f;
        s2 += outl ? prob1 : 0.f;
        s3 += outl ? wgt : 0.f;

        // ---- roll windows ----
        #pragma unroll
        for (int k = 0; k < 7; ++k) m[k] = m[k + 1];
        m[7] = mnew;
        tq[0] = tq[1]; tq[1] = tq[2]; tq[2] = tq[3]; tq[3] = t0;
    }

    // ---- wave reduce (floats); counters already wave-uniform totals ----
    #pragma unroll
    for (int off = 32; off >= 1; off >>= 1) {
        s0 += __shfl_down(s0, off, 64);
        s1 += __shfl_down(s1, off, 64);
        s2 += __shfl_down(s2, off, 64);
        s3 += __shfl_down(s3, off, 64);
    }
    if (lane == 0) {
        redf[wave][0] = s0; redf[wave][1] = s1; redf[wave][2] = s2; redf[wave][3] = s3;
        redi[wave][0] = c_t1; redi[wave][1] = c_bm; redi[wave][2] = c_ok;
    }
    __syncthreads();
    if (tid == 0) {
        float f0 = redf[0][0] + redf[1][0] + redf[2][0] + redf[3][0];
        float f1 = redf[0][1] + redf[1][1] + redf[2][1] + redf[3][1];
        float f2 = redf[0][2] + redf[1][2] + redf[2][2] + redf[3][2];
        float f3 = redf[0][3] + redf[1][3] + redf[2][3] + redf[3][3];
        int i0 = redi[0][0] + redi[1][0] + redi[2][0] + redi[3][0];
        int i1 = redi[0][1] + redi[1][1] + redi[2][1] + redi[3][1];
        int i2 = redi[0][2] + redi[1][2] + redi[2][2] + redi[3][2];
        const int blk = blockIdx.x;
        partials[0 * NBLK + blk] = f0;          // sum ce*w
        partials[1 * NBLK + blk] = f1;          // sum p1*t1
        partials[2 * NBLK + blk] = f2;          // sum p1
        partials[3 * NBLK + blk] = (float)i0;   // sum t1
        partials[4 * NBLK + blk] = f3;          // sum w
        partials[5 * NBLK + blk] = (float)i1;   // cnt
        partials[6 * NBLK + blk] = (float)i2;   // correct
    }
}

__global__ __launch_bounds__(256) void seg_final(const float* __restrict__ partials,
                                                 float* __restrict__ out) {
    __shared__ double red[4][7];
    const int tid = threadIdx.x;
    const int wave = tid >> 6, lane = tid & 63;

    // 640 floats per quantity = 160 float4; threads 0..159 load one each.
    double s[7] = {0, 0, 0, 0, 0, 0, 0};
    if (tid < 160) {
        const float4* p4 = (const float4*)partials;
        #pragma unroll
        for (int k = 0; k < 7; ++k) {
            float4 v = p4[k * 160 + tid];
            s[k] = (((double)v.x + v.y) + ((double)v.z + v.w));
        }
    }
    #pragma unroll
    for (int off = 32; off >= 1; off >>= 1) {
        #pragma unroll
        for (int k = 0; k < 7; ++k) s[k] += __shfl_down(s[k], off, 64);
    }
    if (lane == 0) {
        #pragma unroll
        for (int k = 0; k < 7; ++k) red[wave][k] = s[k];
    }
    __syncthreads();
    if (tid == 0) {
        double f[7];
        #pragma unroll
        for (int k = 0; k < 7; ++k)
            f[k] = red[0][k] + red[1][k] + red[2][k] + red[3][k];
        const double N = (double)B * H * W;
        double wce = f[0] / N;
        double dice = (2.0 * f[1] + 1.0) / (f[2] + f[3] + 1.0);
        double dl = 1.0 - dice;
        double bacc = (f[5] > 0.0) ? (f[6] / f[5]) : 0.0;
        double aw = f[4] / N;
        out[0] = (float)(wce + dl);
        out[1] = (float)wce;
        out[2] = (float)dl;
        out[3] = (float)bacc;
        out[4] = (float)aw;
    }
}

extern "C" void kernel_launch(void* const* d_in, const int* in_sizes, int n_in,
                              void* d_out, int out_size, void* d_ws, size_t ws_size,
                              hipStream_t stream) {
    const float* preds = (const float*)d_in[0];
    const int* tgt = (const int*)d_in[1];
    float* partials = (float*)d_ws;  // needs 7 * 640 * 4 = 17,920 bytes

    seg_main<<<NBLK, 256, 0, stream>>>(preds, tgt, partials);
    seg_final<<<1, 256, 0, stream>>>(partials, (float*)d_out);
}

// Round 7
// 25.953 us; speedup vs baseline: 1.2064x; 1.2064x over previous
//
#include <hip/hip_runtime.h>
#include <stdint.h>

#define H 512
#define W 512
#define B 8
#define TW 32
#define TILEH 32
#define NBX (W / TW)          // 16
#define NBY (H / TILEH)       // 16
#define NBLK (NBX * NBY * B)  // 2048
#define NT 512                // threads per block (8 waves)

// R4 structure, 512-thread blocks: 32x32 tile, preds prefetched at kernel top,
// edge bitmasks via wave ballot (40x40 halo, 5 rows/wave -> half the serial
// chain), target tile in LDS, clipped EDT from folded row bitmasks with
// branchless nearest-bit, 2 px/thread stats, ballot+popc indicators,
// shuffle reduce -> 7 per-block partials. No atomics.
__global__ __launch_bounds__(NT) void seg_main(const float* __restrict__ preds,
                                               const int* __restrict__ tgt,
                                               float* __restrict__ partials) {
    __shared__ unsigned long long emask[40];   // rows by0-4 .. by0+35; bit c <-> ex = bx0-4+c
    __shared__ unsigned char tileT[32][32];    // target classes of the owned tile
    __shared__ float redf[8][4];
    __shared__ int redi[8][3];

    const int tid = threadIdx.x;
    const int wave = tid >> 6;   // 0..7
    const int lane = tid & 63;

    const int bx0 = blockIdx.x * TW;
    const int by0 = blockIdx.y * TILEH;
    const int b = blockIdx.z;
    const int blk = blockIdx.x + NBX * (blockIdx.y + NBY * blockIdx.z);

    const int* T = tgt + (size_t)b * H * W;
    const float* Pb = preds + (size_t)b * 3 * H * W;

    // ---- compute mapping: 1 row x 2 consecutive cols per thread ----
    const int row = tid >> 4;        // 0..31
    const int cg = tid & 15;         // col group: cols 2cg..2cg+1
    const int gy = by0 + row;
    const int gx0 = bx0 + 2 * cg;

    // ---- issue prediction loads FIRST (latency hides under edge phase) ----
    const size_t pix = (size_t)gy * W + gx0;
    const float2 q0 = *(const float2*)(Pb + pix);
    const float2 q1 = *(const float2*)(Pb + pix + (size_t)H * W);
    const float2 q2 = *(const float2*)(Pb + pix + (size_t)2 * H * W);

    // ---- build 40 edge-row bitmasks (5 rows/wave) and stash tile classes ----
    {
        const int ex = bx0 - 4 + lane;
        const bool xok = (lane < 40) & (ex >= 0) & (ex < W);
        const int r0 = wave * 5;
        int ey = by0 - 4 + r0;
        int tup = 0;
        if (xok && (ey - 1) >= 0) tup = T[(ey - 1) * W + ex];
        #pragma unroll
        for (int i = 0; i < 5; ++i, ++ey) {
            const int r = r0 + i;
            const bool rok = xok & (ey >= 0) & (ey < H);
            int t0 = rok ? T[ey * W + ex] : 0;
            int tl = __shfl_up(t0, 1, 64);
            if (lane == 0) tl = (rok & (ex > 0)) ? T[ey * W + ex - 1] : t0;
            bool e = rok & ((((ey > 0) & (t0 != tup))) | (((ex > 0) & (t0 != tl))));
            unsigned long long m = __ballot(e);
            if (lane == 0) emask[r] = m;
            if ((r >= 4) & (r < 36) & (lane >= 4) & (lane < 36))
                tileT[r - 4][lane - 4] = (unsigned char)t0;
            tup = t0;
        }
    }
    __syncthreads();

    const uchar2 tt = *(const uchar2*)&tileT[row][2 * cg];

    unsigned long long rowm[5];
    rowm[0] = emask[row + 4];
    #pragma unroll
    for (int a = 1; a <= 4; ++a) rowm[a] = emask[row + 4 + a] | emask[row + 4 - a];

    const unsigned int allowA[5] = {0x1FFu, 0x1FFu, 0x1FFu, 0xFEu, 0x7Cu};

    float s0 = 0.f, s1 = 0.f, s2 = 0.f, s3 = 0.f;  // ce*w, p1*t1, p1, w
    int c_t1 = 0, c_bm = 0, c_ok = 0;

    #pragma unroll
    for (int c = 0; c < 2; ++c) {
        const int px = 2 * cg + c;
        int d2min = 25;
        #pragma unroll
        for (int a = 0; a < 5; ++a) {
            unsigned int bb = (unsigned int)(rowm[a] >> px) & allowA[a];
            // nearest set bit to center (bit 4): fold sides, ctz; empty -> ax=5
            unsigned int u = ((bb >> 4) & 31u) | (__brev(bb & 31u) >> 27) | 0x20u;
            int ax = __ffs(u) - 1;
            d2min = min(d2min, a * a + ax * ax);
        }
        float dist = (d2min >= 25) ? 5.0f : sqrtf((float)d2min);
        float wgt = (d2min >= 25) ? 1.0f : (2.0f - dist * 0.2f);

        const int t = (c == 0) ? tt.x : tt.y;
        const float p0 = (c == 0) ? q0.x : q0.y;
        const float p1 = (c == 0) ? q1.x : q1.y;
        const float p2 = (c == 0) ? q2.x : q2.y;

        // softmax without max-sub: inputs ~N(0,1), no overflow risk
        float e0 = __expf(p0), e1 = __expf(p1), e2 = __expf(p2);
        float se = e0 + e1 + e2;
        float lse = __logf(se);
        float pt = (t == 0) ? p0 : ((t == 1) ? p1 : p2);
        float ce = lse - pt;
        float prob1 = e1 * __builtin_amdgcn_rcpf(se);

        int cls = 0;
        float best = p0;
        if (p1 > best) { best = p1; cls = 1; }
        if (p2 > best) { cls = 2; }

        bool bm = wgt > 1.5f;
        bool ok = bm & (cls == t);
        c_t1 += __popcll(__ballot(t == 1));
        c_bm += __popcll(__ballot(bm));
        c_ok += __popcll(__ballot(ok));

        s0 += ce * wgt;
        s1 += (t == 1) ? prob1 : 0.0f;
        s2 += prob1;
        s3 += wgt;
    }

    #pragma unroll
    for (int off = 32; off >= 1; off >>= 1) {
        s0 += __shfl_down(s0, off, 64);
        s1 += __shfl_down(s1, off, 64);
        s2 += __shfl_down(s2, off, 64);
        s3 += __shfl_down(s3, off, 64);
    }
    if (lane == 0) {
        redf[wave][0] = s0; redf[wave][1] = s1; redf[wave][2] = s2; redf[wave][3] = s3;
        redi[wave][0] = c_t1; redi[wave][1] = c_bm; redi[wave][2] = c_ok;
    }
    __syncthreads();
    if (tid == 0) {
        float f0 = 0.f, f1 = 0.f, f2 = 0.f, f3 = 0.f;
        int i0 = 0, i1 = 0, i2 = 0;
        #pragma unroll
        for (int wv = 0; wv < 8; ++wv) {
            f0 += redf[wv][0]; f1 += redf[wv][1]; f2 += redf[wv][2]; f3 += redf[wv][3];
            i0 += redi[wv][0]; i1 += redi[wv][1]; i2 += redi[wv][2];
        }
        partials[0 * NBLK + blk] = f0;          // sum ce*w
        partials[1 * NBLK + blk] = f1;          // sum p1*t1
        partials[2 * NBLK + blk] = f2;          // sum p1
        partials[3 * NBLK + blk] = (float)i0;   // sum t1
        partials[4 * NBLK + blk] = f3;          // sum w
        partials[5 * NBLK + blk] = (float)i1;   // cnt
        partials[6 * NBLK + blk] = (float)i2;   // correct
    }
}

__global__ __launch_bounds__(256) void seg_final(const float* __restrict__ partials,
                                                 float* __restrict__ out) {
    __shared__ double red[4][7];
    const int tid = threadIdx.x;
    const int wave = tid >> 6, lane = tid & 63;

    // 2048 floats per quantity = 512 float4; 256 threads x 2 float4 each.
    const float4* p4 = (const float4*)partials;
    float4 va[7], vb[7];
    #pragma unroll
    for (int k = 0; k < 7; ++k) {
        va[k] = p4[k * 512 + tid];
        vb[k] = p4[k * 512 + 256 + tid];
    }
    double s[7];
    #pragma unroll
    for (int k = 0; k < 7; ++k)
        s[k] = (((double)va[k].x + va[k].y) + ((double)va[k].z + va[k].w)) +
               (((double)vb[k].x + vb[k].y) + ((double)vb[k].z + vb[k].w));

    #pragma unroll
    for (int off = 32; off >= 1; off >>= 1) {
        #pragma unroll
        for (int k = 0; k < 7; ++k) s[k] += __shfl_down(s[k], off, 64);
    }
    if (lane == 0) {
        #pragma unroll
        for (int k = 0; k < 7; ++k) red[wave][k] = s[k];
    }
    __syncthreads();
    if (tid == 0) {
        double f[7];
        #pragma unroll
        for (int k = 0; k < 7; ++k)
            f[k] = red[0][k] + red[1][k] + red[2][k] + red[3][k];
        const double N = (double)B * H * W;
        double wce = f[0] / N;
        double dice = (2.0 * f[1] + 1.0) / (f[2] + f[3] + 1.0);
        double dl = 1.0 - dice;
        double bacc = (f[5] > 0.0) ? (f[6] / f[5]) : 0.0;
        double aw = f[4] / N;
        out[0] = (float)(wce + dl);
        out[1] = (float)wce;
        out[2] = (float)dl;
        out[3] = (float)bacc;
        out[4] = (float)aw;
    }
}

extern "C" void kernel_launch(void* const* d_in, const int* in_sizes, int n_in,
                              void* d_out, int out_size, void* d_ws, size_t ws_size,
                              hipStream_t stream) {
    const float* preds = (const float*)d_in[0];
    const int* tgt = (const int*)d_in[1];
    float* partials = (float*)d_ws;  // needs 7 * 2048 * 4 = 57,344 bytes

    dim3 grid(NBX, NBY, B);
    seg_main<<<grid, NT, 0, stream>>>(preds, tgt, partials);
    seg_final<<<1, 256, 0, stream>>>(partials, (float*)d_out);
}

// Round 8
// 22.350 us; speedup vs baseline: 1.4009x; 1.1612x over previous
//
#include <hip/hip_runtime.h>
#include <stdint.h>

#define H 512
#define W 512
#define B 8
#define TW 32
#define TILEH 32
#define NBX (W / TW)          // 16
#define NBY (H / TILEH)       // 16
#define NBLK (NBX * NBY * B)  // 2048

// R4 structure + LDS LUTs:
//  - preds float4 loads issued first (hide under edge phase)
//  - edge bitmasks via wave ballot, 41 active lanes (left neighbor via shfl_up
//    only, mask = ballot>>1; no divergent lane-0 load)
//  - nearlut[512]: 9-bit window -> capped nearest-ax^2 (EDT window = 5 insts)
//  - wlut[26]: d2min -> weight (kills sqrt/select chain)
//  - target tile in LDS; ballot+popc indicators; shuffle reduce -> partials
__global__ __launch_bounds__(256) void seg_main(const float* __restrict__ preds,
                                                const int* __restrict__ tgt,
                                                float* __restrict__ partials) {
    __shared__ unsigned long long emask[40];   // rows by0-4 .. by0+35; bit c <-> col bx0-4+c
    __shared__ unsigned char tileT[32][32];    // target classes of the owned tile
    __shared__ unsigned char nearlut[512];     // 9-bit window -> min(ax^2, 25)
    __shared__ float wlut[26];                 // d2min -> weight
    __shared__ float redf[4][4];
    __shared__ int redi[4][3];

    const int lx = threadIdx.x;  // 0..31
    const int ly = threadIdx.y;  // 0..7
    const int tid = ly * 32 + lx;
    const int wave = tid >> 6;
    const int lane = tid & 63;

    const int bx0 = blockIdx.x * TW;
    const int by0 = blockIdx.y * TILEH;
    const int b = blockIdx.z;
    const int blk = blockIdx.x + NBX * (blockIdx.y + NBY * blockIdx.z);

    const int* T = tgt + (size_t)b * H * W;
    const float* Pb = preds + (size_t)b * 3 * H * W;

    // ---- fill LUTs (before the barrier) ----
    #pragma unroll
    for (int k = 0; k < 2; ++k) {
        const int idx = tid + 256 * k;
        unsigned int u = (((unsigned)idx >> 4) & 31u) |
                         (__brev((unsigned)idx & 31u) >> 27) | 0x20u;
        int ax = __ffs(u) - 1;
        nearlut[idx] = (unsigned char)min(ax * ax, 25);
    }
    if (tid < 26)
        wlut[tid] = (tid >= 25) ? 1.0f : (2.0f - sqrtf((float)tid) * 0.2f);

    // ---- compute mapping: 1 row x 4 consecutive cols per thread ----
    const int g = lx & 7;               // column group: cols 4g..4g+3
    const int row = ly * 4 + (lx >> 3); // tile row 0..31
    const int gy = by0 + row;
    const int gx0 = bx0 + 4 * g;

    // ---- issue prediction loads FIRST (latency hides under edge phase) ----
    const size_t pix = (size_t)gy * W + gx0;
    const float4 q0 = *(const float4*)(Pb + pix);
    const float4 q1 = *(const float4*)(Pb + pix + (size_t)H * W);
    const float4 q2 = *(const float4*)(Pb + pix + (size_t)2 * H * W);

    // ---- build 40 edge-row bitmasks (10 rows/wave), stash tile classes ----
    {
        const int ex = bx0 - 5 + lane;              // lanes 0..40 cover cols bx0-5..bx0+35
        const bool xok = (lane <= 40) & (ex >= 0) & (ex < W);
        const int r0 = wave * 10;
        int ey = by0 - 4 + r0;
        int tup = 0;
        if (xok && (ey - 1) >= 0) tup = T[(ey - 1) * W + ex];
        #pragma unroll
        for (int i = 0; i < 10; ++i, ++ey) {
            const int r = r0 + i;
            const bool rok = xok & (ey >= 0) & (ey < H);
            int t0 = rok ? T[ey * W + ex] : 0;
            int tl = __shfl_up(t0, 1, 64);
            bool e = rok & ((((ey > 0) & (t0 != tup))) | (((ex > 0) & (t0 != tl))));
            unsigned long long m = __ballot(e) >> 1;   // bit c <-> col bx0-4+c
            if (lane == 0) emask[r] = m;
            if ((r >= 4) & (r < 36) & (lane >= 5) & (lane <= 36))
                tileT[r - 4][lane - 5] = (unsigned char)t0;
            tup = t0;
        }
    }
    __syncthreads();

    const uchar4 tt = *(const uchar4*)&tileT[row][4 * g];

    unsigned long long rowm[5];
    rowm[0] = emask[row + 4];
    #pragma unroll
    for (int a = 1; a <= 4; ++a) rowm[a] = emask[row + 4 + a] | emask[row + 4 - a];

    const unsigned int allowA[5] = {0x1FFu, 0x1FFu, 0x1FFu, 0xFEu, 0x7Cu};
    const int a2c[5] = {0, 1, 4, 9, 16};

    float s0 = 0.f, s1 = 0.f, s2 = 0.f, s3 = 0.f;  // ce*w, p1*t1, p1, w
    int c_t1 = 0, c_bm = 0, c_ok = 0;

    #pragma unroll
    for (int c = 0; c < 4; ++c) {
        const int px = 4 * g + c;
        int d2min = 25;
        #pragma unroll
        for (int a = 0; a < 5; ++a) {
            unsigned int bb = (unsigned int)(rowm[a] >> px) & allowA[a];
            d2min = min(d2min, a2c[a] + (int)nearlut[bb]);
        }
        const float wgt = wlut[d2min];

        const int t = (c == 0) ? tt.x : ((c == 1) ? tt.y : ((c == 2) ? tt.z : tt.w));
        const float p0 = (c == 0) ? q0.x : ((c == 1) ? q0.y : ((c == 2) ? q0.z : q0.w));
        const float p1 = (c == 0) ? q1.x : ((c == 1) ? q1.y : ((c == 2) ? q1.z : q1.w));
        const float p2 = (c == 0) ? q2.x : ((c == 1) ? q2.y : ((c == 2) ? q2.z : q2.w));

        // softmax without max-sub: inputs ~N(0,1), no overflow risk
        float e0 = __expf(p0), e1 = __expf(p1), e2 = __expf(p2);
        float se = e0 + e1 + e2;
        float lse = __logf(se);
        float pt = (t == 0) ? p0 : ((t == 1) ? p1 : p2);
        float ce = lse - pt;
        float prob1 = e1 * __builtin_amdgcn_rcpf(se);

        int cls = 0;
        float best = p0;
        if (p1 > best) { best = p1; cls = 1; }
        if (p2 > best) { cls = 2; }

        bool bm = wgt > 1.5f;
        bool ok = bm & (cls == t);
        c_t1 += __popcll(__ballot(t == 1));
        c_bm += __popcll(__ballot(bm));
        c_ok += __popcll(__ballot(ok));

        s0 += ce * wgt;
        s1 += (t == 1) ? prob1 : 0.0f;
        s2 += prob1;
        s3 += wgt;
    }

    #pragma unroll
    for (int off = 32; off >= 1; off >>= 1) {
        s0 += __shfl_down(s0, off, 64);
        s1 += __shfl_down(s1, off, 64);
        s2 += __shfl_down(s2, off, 64);
        s3 += __shfl_down(s3, off, 64);
    }
    if (lane == 0) {
        redf[wave][0] = s0; redf[wave][1] = s1; redf[wave][2] = s2; redf[wave][3] = s3;
        redi[wave][0] = c_t1; redi[wave][1] = c_bm; redi[wave][2] = c_ok;
    }
    __syncthreads();
    if (tid == 0) {
        float f0 = redf[0][0] + redf[1][0] + redf[2][0] + redf[3][0];
        float f1 = redf[0][1] + redf[1][1] + redf[2][1] + redf[3][1];
        float f2 = redf[0][2] + redf[1][2] + redf[2][2] + redf[3][2];
        float f3 = redf[0][3] + redf[1][3] + redf[2][3] + redf[3][3];
        int i0 = redi[0][0] + redi[1][0] + redi[2][0] + redi[3][0];
        int i1 = redi[0][1] + redi[1][1] + redi[2][1] + redi[3][1];
        int i2 = redi[0][2] + redi[1][2] + redi[2][2] + redi[3][2];
        partials[0 * NBLK + blk] = f0;          // sum ce*w
        partials[1 * NBLK + blk] = f1;          // sum p1*t1
        partials[2 * NBLK + blk] = f2;          // sum p1
        partials[3 * NBLK + blk] = (float)i0;   // sum t1
        partials[4 * NBLK + blk] = f3;          // sum w
        partials[5 * NBLK + blk] = (float)i1;   // cnt
        partials[6 * NBLK + blk] = (float)i2;   // correct
    }
}

__global__ __launch_bounds__(256) void seg_final(const float* __restrict__ partials,
                                                 float* __restrict__ out) {
    __shared__ double red[4][7];
    const int tid = threadIdx.x;
    const int wave = tid >> 6, lane = tid & 63;

    // 2048 floats per quantity = 512 float4; 256 threads x 2 float4 each.
    const float4* p4 = (const float4*)partials;
    float4 va[7], vb[7];
    #pragma unroll
    for (int k = 0; k < 7; ++k) {
        va[k] = p4[k * 512 + tid];
        vb[k] = p4[k * 512 + 256 + tid];
    }
    double s[7];
    #pragma unroll
    for (int k = 0; k < 7; ++k)
        s[k] = (((double)va[k].x + va[k].y) + ((double)va[k].z + va[k].w)) +
               (((double)vb[k].x + vb[k].y) + ((double)vb[k].z + vb[k].w));

    #pragma unroll
    for (int off = 32; off >= 1; off >>= 1) {
        #pragma unroll
        for (int k = 0; k < 7; ++k) s[k] += __shfl_down(s[k], off, 64);
    }
    if (lane == 0) {
        #pragma unroll
        for (int k = 0; k < 7; ++k) red[wave][k] = s[k];
    }
    __syncthreads();
    if (tid == 0) {
        double f[7];
        #pragma unroll
        for (int k = 0; k < 7; ++k)
            f[k] = red[0][k] + red[1][k] + red[2][k] + red[3][k];
        const double N = (double)B * H * W;
        double wce = f[0] / N;
        double dice = (2.0 * f[1] + 1.0) / (f[2] + f[3] + 1.0);
        double dl = 1.0 - dice;
        double bacc = (f[5] > 0.0) ? (f[6] / f[5]) : 0.0;
        double aw = f[4] / N;
        out[0] = (float)(wce + dl);
        out[1] = (float)wce;
        out[2] = (float)dl;
        out[3] = (float)bacc;
        out[4] = (float)aw;
    }
}

extern "C" void kernel_launch(void* const* d_in, const int* in_sizes, int n_in,
                              void* d_out, int out_size, void* d_ws, size_t ws_size,
                              hipStream_t stream) {
    const float* preds = (const float*)d_in[0];
    const int* tgt = (const int*)d_in[1];
    float* partials = (float*)d_ws;  // needs 7 * 2048 * 4 = 57,344 bytes

    dim3 grid(NBX, NBY, B);
    dim3 block(TW, 8);
    seg_main<<<grid, block, 0, stream>>>(preds, tgt, partials);
    seg_final<<<1, 256, 0, stream>>>(partials, (float*)d_out);
}

// Round 9
// 20.375 us; speedup vs baseline: 1.5367x; 1.0969x over previous
//
#include <hip/hip_runtime.h>
#include <stdint.h>

#define H 512
#define W 512
#define B 8
#define TW 32
#define TILEH 32
#define NBX (W / TW)          // 16
#define NBY (H / TILEH)       // 16
#define NBLK (NBX * NBY * B)  // 2048

// R8 structure with load-order fix:
//  phase 1: all T halo loads -> register array (independent, issued first)
//  phase 2: preds float4 loads (complete under ballot work, NOT in chain path)
//  phase 3: ballot chain from registers (41 active lanes, mask = ballot>>1)
//  nearlut[512] 9-bit window -> capped ax^2; wlut[26] d2 -> weight
//  2-exp softmax (sp = e^(p0-p1)+1+e^(p2-p1)); ballot+popc indicators;
//  shuffle reduce -> 7 per-block partials. No atomics.
__global__ __launch_bounds__(256) void seg_main(const float* __restrict__ preds,
                                                const int* __restrict__ tgt,
                                                float* __restrict__ partials) {
    __shared__ unsigned long long emask[40];   // rows by0-4 .. by0+35; bit c <-> col bx0-4+c
    __shared__ unsigned char tileT[32][32];    // target classes of the owned tile
    __shared__ unsigned char nearlut[512];     // 9-bit window -> min(ax^2, 25)
    __shared__ float wlut[26];                 // d2min -> weight
    __shared__ float redf[4][4];
    __shared__ int redi[4][3];

    const int lx = threadIdx.x;  // 0..31
    const int ly = threadIdx.y;  // 0..7
    const int tid = ly * 32 + lx;
    const int wave = tid >> 6;
    const int lane = tid & 63;

    const int bx0 = blockIdx.x * TW;
    const int by0 = blockIdx.y * TILEH;
    const int b = blockIdx.z;
    const int blk = blockIdx.x + NBX * (blockIdx.y + NBY * blockIdx.z);

    const int* T = tgt + (size_t)b * H * W;
    const float* Pb = preds + (size_t)b * 3 * H * W;

    // ---- phase 1: T halo loads into registers (all independent) ----
    const int ex = bx0 - 5 + lane;              // lanes 0..40 cover cols bx0-5..bx0+35
    const bool xok = (lane <= 40) & (ex >= 0) & (ex < W);
    const int r0 = wave * 10;
    const int ey0 = by0 - 4 + r0;
    int trow[10];
    int tup0 = 0;
    if (xok && (ey0 - 1) >= 0) tup0 = T[(size_t)(ey0 - 1) * W + ex];
    #pragma unroll
    for (int i = 0; i < 10; ++i) {
        const int ey = ey0 + i;
        const bool rok = xok & (ey >= 0) & (ey < H);
        trow[i] = rok ? T[(size_t)ey * W + ex] : 0;
    }

    // ---- phase 2: preds loads (latency hides under ballot chain) ----
    const int g = lx & 7;               // column group: cols 4g..4g+3
    const int row = ly * 4 + (lx >> 3); // tile row 0..31
    const int gy = by0 + row;
    const int gx0 = bx0 + 4 * g;
    const size_t pix = (size_t)gy * W + gx0;
    const float4 q0 = *(const float4*)(Pb + pix);
    const float4 q1 = *(const float4*)(Pb + pix + (size_t)H * W);
    const float4 q2 = *(const float4*)(Pb + pix + (size_t)2 * H * W);

    // ---- fill LUTs ----
    #pragma unroll
    for (int k = 0; k < 2; ++k) {
        const int idx = tid + 256 * k;
        unsigned int u = (((unsigned)idx >> 4) & 31u) |
                         (__brev((unsigned)idx & 31u) >> 27) | 0x20u;
        int ax = __ffs(u) - 1;
        nearlut[idx] = (unsigned char)min(ax * ax, 25);
    }
    if (tid < 26)
        wlut[tid] = (tid >= 25) ? 1.0f : (2.0f - sqrtf((float)tid) * 0.2f);

    // ---- phase 3: ballot chain from registers, stash tile classes ----
    {
        int tup = tup0;
        #pragma unroll
        for (int i = 0; i < 10; ++i) {
            const int r = r0 + i;
            const int ey = ey0 + i;
            int t0 = trow[i];
            int tl = __shfl_up(t0, 1, 64);
            bool e = xok & (ey >= 0) & (ey < H) &
                     ((((ey > 0) & (t0 != tup))) | (((ex > 0) & (t0 != tl))));
            unsigned long long m = __ballot(e) >> 1;   // bit c <-> col bx0-4+c
            if (lane == 0) emask[r] = m;
            if ((r >= 4) & (r < 36) & (lane >= 5) & (lane <= 36))
                tileT[r - 4][lane - 5] = (unsigned char)t0;
            tup = t0;
        }
    }
    __syncthreads();

    const uchar4 tt = *(const uchar4*)&tileT[row][4 * g];

    unsigned long long rowm[5];
    rowm[0] = emask[row + 4];
    #pragma unroll
    for (int a = 1; a <= 4; ++a) rowm[a] = emask[row + 4 + a] | emask[row + 4 - a];

    const unsigned int allowA[5] = {0x1FFu, 0x1FFu, 0x1FFu, 0xFEu, 0x7Cu};
    const int a2c[5] = {0, 1, 4, 9, 16};

    float s0 = 0.f, s1 = 0.f, s2 = 0.f, s3 = 0.f;  // ce*w, p1*t1, p1, w
    int c_t1 = 0, c_bm = 0, c_ok = 0;

    #pragma unroll
    for (int c = 0; c < 4; ++c) {
        const int px = 4 * g + c;
        int d2min = 25;
        #pragma unroll
        for (int a = 0; a < 5; ++a) {
            unsigned int bb = (unsigned int)(rowm[a] >> px) & allowA[a];
            d2min = min(d2min, a2c[a] + (int)nearlut[bb]);
        }
        const float wgt = wlut[d2min];

        const int t = (c == 0) ? tt.x : ((c == 1) ? tt.y : ((c == 2) ? tt.z : tt.w));
        const float p0 = (c == 0) ? q0.x : ((c == 1) ? q0.y : ((c == 2) ? q0.z : q0.w));
        const float p1 = (c == 0) ? q1.x : ((c == 1) ? q1.y : ((c == 2) ? q1.z : q1.w));
        const float p2 = (c == 0) ? q2.x : ((c == 1) ? q2.y : ((c == 2) ? q2.z : q2.w));

        // 2-exp softmax relative to p1 (inputs ~N(0,1), no overflow risk):
        // sp = e^(p0-p1) + 1 + e^(p2-p1); lse = p1 + log(sp); prob1 = 1/sp
        float e0 = __expf(p0 - p1), e2 = __expf(p2 - p1);
        float sp = e0 + 1.0f + e2;
        float lse = p1 + __logf(sp);
        float pt = (t == 0) ? p0 : ((t == 1) ? p1 : p2);
        float ce = lse - pt;
        float prob1 = __builtin_amdgcn_rcpf(sp);

        int cls = 0;
        float best = p0;
        if (p1 > best) { best = p1; cls = 1; }
        if (p2 > best) { cls = 2; }

        bool bm = wgt > 1.5f;
        bool ok = bm & (cls == t);
        c_t1 += __popcll(__ballot(t == 1));
        c_bm += __popcll(__ballot(bm));
        c_ok += __popcll(__ballot(ok));

        s0 += ce * wgt;
        s1 += (t == 1) ? prob1 : 0.0f;
        s2 += prob1;
        s3 += wgt;
    }

    #pragma unroll
    for (int off = 32; off >= 1; off >>= 1) {
        s0 += __shfl_down(s0, off, 64);
        s1 += __shfl_down(s1, off, 64);
        s2 += __shfl_down(s2, off, 64);
        s3 += __shfl_down(s3, off, 64);
    }
    if (lane == 0) {
        redf[wave][0] = s0; redf[wave][1] = s1; redf[wave][2] = s2; redf[wave][3] = s3;
        redi[wave][0] = c_t1; redi[wave][1] = c_bm; redi[wave][2] = c_ok;
    }
    __syncthreads();
    if (tid == 0) {
        float f0 = redf[0][0] + redf[1][0] + redf[2][0] + redf[3][0];
        float f1 = redf[0][1] + redf[1][1] + redf[2][1] + redf[3][1];
        float f2 = redf[0][2] + redf[1][2] + redf[2][2] + redf[3][2];
        float f3 = redf[0][3] + redf[1][3] + redf[2][3] + redf[3][3];
        int i0 = redi[0][0] + redi[1][0] + redi[2][0] + redi[3][0];
        int i1 = redi[0][1] + redi[1][1] + redi[2][1] + redi[3][1];
        int i2 = redi[0][2] + redi[1][2] + redi[2][2] + redi[3][2];
        partials[0 * NBLK + blk] = f0;          // sum ce*w
        partials[1 * NBLK + blk] = f1;          // sum p1*t1
        partials[2 * NBLK + blk] = f2;          // sum p1
        partials[3 * NBLK + blk] = (float)i0;   // sum t1
        partials[4 * NBLK + blk] = f3;          // sum w
        partials[5 * NBLK + blk] = (float)i1;   // cnt
        partials[6 * NBLK + blk] = (float)i2;   // correct
    }
}

__global__ __launch_bounds__(256) void seg_final(const float* __restrict__ partials,
                                                 float* __restrict__ out) {
    __shared__ double red[4][7];
    const int tid = threadIdx.x;
    const int wave = tid >> 6, lane = tid & 63;

    // 2048 floats per quantity = 512 float4; 256 threads x 2 float4 each.
    const float4* p4 = (const float4*)partials;
    float4 va[7], vb[7];
    #pragma unroll
    for (int k = 0; k < 7; ++k) {
        va[k] = p4[k * 512 + tid];
        vb[k] = p4[k * 512 + 256 + tid];
    }
    double s[7];
    #pragma unroll
    for (int k = 0; k < 7; ++k)
        s[k] = (((double)va[k].x + va[k].y) + ((double)va[k].z + va[k].w)) +
               (((double)vb[k].x + vb[k].y) + ((double)vb[k].z + vb[k].w));

    #pragma unroll
    for (int off = 32; off >= 1; off >>= 1) {
        #pragma unroll
        for (int k = 0; k < 7; ++k) s[k] += __shfl_down(s[k], off, 64);
    }
    if (lane == 0) {
        #pragma unroll
        for (int k = 0; k < 7; ++k) red[wave][k] = s[k];
    }
    __syncthreads();
    if (tid == 0) {
        double f[7];
        #pragma unroll
        for (int k = 0; k < 7; ++k)
            f[k] = red[0][k] + red[1][k] + red[2][k] + red[3][k];
        const double N = (double)B * H * W;
        double wce = f[0] / N;
        double dice = (2.0 * f[1] + 1.0) / (f[2] + f[3] + 1.0);
        double dl = 1.0 - dice;
        double bacc = (f[5] > 0.0) ? (f[6] / f[5]) : 0.0;
        double aw = f[4] / N;
        out[0] = (float)(wce + dl);
        out[1] = (float)wce;
        out[2] = (float)dl;
        out[3] = (float)bacc;
        out[4] = (float)aw;
    }
}

extern "C" void kernel_launch(void* const* d_in, const int* in_sizes, int n_in,
                              void* d_out, int out_size, void* d_ws, size_t ws_size,
                              hipStream_t stream) {
    const float* preds = (const float*)d_in[0];
    const int* tgt = (const int*)d_in[1];
    float* partials = (float*)d_ws;  // needs 7 * 2048 * 4 = 57,344 bytes

    dim3 grid(NBX, NBY, B);
    dim3 block(TW, 8);
    seg_main<<<grid, block, 0, stream>>>(preds, tgt, partials);
    seg_final<<<1, 256, 0, stream>>>(partials, (float*)d_out);
}